// Round 7
// baseline (6513.746 us; speedup 1.0000x reference)
//
#include <hip/hip_runtime.h>

// y = alpha*(x @ Q^T) + bias; alpha = mean|W|; Q = clip(round(W/alpha),-1,1)
// x:(2,4096,4096) f32, W:(16384,4096) f32, bias:(16384) f32, out f32.
#define M_DIM 8192
#define N_DIM 16384
#define K_DIM 4096
#define KT 32
#define NT 128  // K_DIM / KT

typedef unsigned short u16;
typedef unsigned int u32;
typedef __attribute__((ext_vector_type(8))) short bf16x8;
typedef __attribute__((ext_vector_type(8))) unsigned short u16x8;
typedef __attribute__((ext_vector_type(4))) float f32x4;

#define MFMA(a, b, c) __builtin_amdgcn_mfma_f32_16x16x32_bf16(a, b, c, 0, 0, 0)

__device__ __forceinline__ void gload16(const u16* g, u16* l) {
  __builtin_amdgcn_global_load_lds((const __attribute__((address_space(1))) void*)g,
                                   (__attribute__((address_space(3))) void*)l, 16, 0, 0);
}

// ---------------- alpha = mean(|W|), f64 two-pass reduction ----------------
__global__ void reduce_abs1(const float* __restrict__ w, double* __restrict__ partials) {
  const float4* w4 = (const float4*)w;
  size_t base = (size_t)blockIdx.x * 4096 + threadIdx.x;
  double s = 0.0;
#pragma unroll
  for (int i = 0; i < 16; ++i) {
    float4 v = w4[base + (size_t)i * 256];
    s += (double)fabsf(v.x); s += (double)fabsf(v.y);
    s += (double)fabsf(v.z); s += (double)fabsf(v.w);
  }
#pragma unroll
  for (int off = 32; off > 0; off >>= 1) s += __shfl_down(s, off, 64);
  __shared__ double red[4];
  int wv = threadIdx.x >> 6, lane = threadIdx.x & 63;
  if (lane == 0) red[wv] = s;
  __syncthreads();
  if (threadIdx.x == 0) partials[blockIdx.x] = (red[0] + red[1]) + (red[2] + red[3]);
}

__global__ void reduce_abs2(const double* __restrict__ partials,
                            double* __restrict__ alpha_d, float* __restrict__ alpha_f) {
  double s = 0.0;
  for (int i = threadIdx.x; i < 4096; i += 256) s += partials[i];
#pragma unroll
  for (int off = 32; off > 0; off >>= 1) s += __shfl_down(s, off, 64);
  __shared__ double red[4];
  int wv = threadIdx.x >> 6, lane = threadIdx.x & 63;
  if (lane == 0) red[wv] = s;
  __syncthreads();
  if (threadIdx.x == 0) {
    double total = (red[0] + red[1]) + (red[2] + red[3]);
    double a = total / (double)((long long)N_DIM * (long long)K_DIM);
    alpha_d[0] = a;
    alpha_f[0] = (float)a;
  }
}

// ---------------- W -> ternary Q stored as bf16 (+1/0/-1 exact) ----------------
__global__ void quant_w(const float* __restrict__ w, const double* __restrict__ alpha_d,
                        u16* __restrict__ q) {
  double inv = 1.0 / alpha_d[0];
  size_t i8 = (size_t)blockIdx.x * 256 + threadIdx.x;
  const float4* w4 = (const float4*)w;
  float4 v0 = w4[i8 * 2], v1 = w4[i8 * 2 + 1];
  float vv[8] = {v0.x, v0.y, v0.z, v0.w, v1.x, v1.y, v1.z, v1.w};
  u16x8 o;
#pragma unroll
  for (int j = 0; j < 8; ++j) {
    double r = rint((double)vv[j] * inv);
    u16 enc = 0;
    if (r >= 1.0) enc = 0x3F80u;
    else if (r <= -1.0) enc = 0xBF80u;
    o[j] = enc;
  }
  *((u16x8*)q + i8) = o;
}

// ---------------- x fp32 -> bf16 (RNE) ----------------
__global__ void conv_x(const float* __restrict__ x, u16* __restrict__ xb) {
  size_t i8 = (size_t)blockIdx.x * 256 + threadIdx.x;
  const float4* x4 = (const float4*)x;
  float4 v0 = x4[i8 * 2], v1 = x4[i8 * 2 + 1];
  float vv[8] = {v0.x, v0.y, v0.z, v0.w, v1.x, v1.y, v1.z, v1.w};
  u16x8 o;
#pragma unroll
  for (int j = 0; j < 8; ++j) {
    u32 u = __float_as_uint(vv[j]);
    u += 0x7FFFu + ((u >> 16) & 1u);
    o[j] = (u16)(u >> 16);
  }
  *((u16x8*)xb + i8) = o;
}

// ------- 512x256-tile bf16 GEMM, 128x128 wave tiles, BK=32 -------
// 512 threads = 8 waves (4M x 2N); per-wave 128x128 output = acc[8][8] f32x4
// (128 AGPR). LDS: 2 buffers x {A 512x32, B 256x32} bf16 = 96 KiB.
// Rationale: LDS-read volume per FLOP drops 1.5x vs 128x64 wave tile (each
// frag read feeds 8 MFMAs, not 4): per-tile walls MFMA 2483cy, LDS 1375cy
// (was 2030). Single barrier per K-tile, opposite-parity depth-1 prefetch
// (stage writes NEVER alias current reads). A4-7 frag reads placed after the
// first 32-MFMA cluster so the compiler can slide them under it (counted
// lgkmcnt). Both-sides XOR swizzle on 4-chunk rows (2-way aliasing = free).
__global__ __launch_bounds__(512, 2) void gemm256(
    const u16* __restrict__ A, const u16* __restrict__ Bq,
    const float* __restrict__ bias, const float* __restrict__ alpha_f,
    float* __restrict__ C) {
  __shared__ __align__(16) u16 Alds[2][512 * KT];  // 32 KiB per parity
  __shared__ __align__(16) u16 Blds[2][256 * KT];  // 16 KiB per parity

  const int t = threadIdx.x;
  const int wv = t >> 6, l = t & 63;
  const int wr = wv >> 1, wc = wv & 1;  // 4M x 2N wave grid
  const int lr = l & 15, lk = l >> 4;

  // XCD-bijective swizzle (1024 % 8 == 0) + 8(tm) x 64(tn) supertiles
  const int bid = blockIdx.x;
  const int wg = (bid & 7) * 128 + (bid >> 3);
  const int grp = wg >> 9, rem = wg & 511;
  const int tm = grp * 8 + (rem & 7);  // 0..15
  const int tn = rem >> 3;             // 0..63

  const u16* Ag = A + (size_t)tm * 512 * K_DIM;
  const u16* Bg = Bq + (size_t)tn * 256 * K_DIM;

  // staging: 16B chunk q of a [rows][KT] tile -> row=q>>2, swizzled chunk
  // c=(q&3)^(row&3); LDS dest linear (wave-uniform base + lane*16).
  int soA[4], soB[2], doA[4], doB[2];
#pragma unroll
  for (int i = 0; i < 4; ++i) {
    int q = i * 512 + t;
    int row = q >> 2, c = (q & 3) ^ (row & 3);
    soA[i] = row * K_DIM + c * 8;
    doA[i] = (i * 512 + wv * 64) * 8;
  }
#pragma unroll
  for (int i = 0; i < 2; ++i) {
    int q = i * 512 + t;
    int row = q >> 2, c = (q & 3) ^ (row & 3);
    soB[i] = row * K_DIM + c * 8;
    doB[i] = (i * 512 + wv * 64) * 8;
  }

  // frag read base (u16 units): row = sub*16 + lr within wave slice;
  // row&3 == lr&3, so per-sub offset = sub*512 folds to an immediate.
  const int fb = lr * KT + ((lk ^ (lr & 3)) * 8);
  const int abase = wr * (128 * KT);  // wave's A slice: 128 rows
  const int bbase = wc * (128 * KT);  // wave's B slice: 128 rows

  f32x4 acc[8][8];
#pragma unroll
  for (int mi = 0; mi < 8; ++mi)
#pragma unroll
    for (int ni = 0; ni < 8; ++ni)
      acc[mi][ni] = (f32x4){0.f, 0.f, 0.f, 0.f};

  // stage K-tile g into parity g&1 (6 x global_load_lds per thread)
  auto stage = [&](int g) {
    if (g < NT) {
      const int par = g & 1;
      const u16* As = Ag + (size_t)g * KT;
      const u16* Bs = Bg + (size_t)g * KT;
#pragma unroll
      for (int i = 0; i < 4; ++i) gload16(As + soA[i], &Alds[par][doA[i]]);
#pragma unroll
      for (int i = 0; i < 2; ++i) gload16(Bs + soB[i], &Blds[par][doB[i]]);
    }
  };

  // one K-tile; par is a compile-time constant at each expansion
#define K_TILE(kt, par)                                                        \
  {                                                                            \
    const u16* Ar = &Alds[par][abase];                                         \
    const u16* Br = &Blds[par][bbase];                                         \
    /* prefetch next tile (opposite parity: never aliases current reads) */   \
    stage((kt) + 1);                                                           \
    __builtin_amdgcn_sched_barrier(0);                                         \
    bf16x8 aF[8], bF[8];                                                       \
    /* reads: all B (8) + A0-3 (4) feed the first MFMA cluster */              \
    _Pragma("unroll") for (int s = 0; s < 8; ++s)                              \
      bF[s] = *(const bf16x8*)(Br + s * 512 + fb);                             \
    _Pragma("unroll") for (int s = 0; s < 4; ++s)                              \
      aF[s] = *(const bf16x8*)(Ar + s * 512 + fb);                             \
    __builtin_amdgcn_s_setprio(1);                                             \
    _Pragma("unroll") for (int m = 0; m < 4; ++m)                              \
      _Pragma("unroll") for (int ni = 0; ni < 8; ++ni)                         \
        acc[m][ni] = MFMA(aF[m], bF[ni], acc[m][ni]);                          \
    __builtin_amdgcn_s_setprio(0);                                             \
    /* A4-7 reads can slide under the cluster above (counted lgkmcnt) */       \
    _Pragma("unroll") for (int s = 4; s < 8; ++s)                              \
      aF[s] = *(const bf16x8*)(Ar + s * 512 + fb);                             \
    __builtin_amdgcn_s_setprio(1);                                             \
    _Pragma("unroll") for (int m = 4; m < 8; ++m)                              \
      _Pragma("unroll") for (int ni = 0; ni < 8; ++ni)                         \
        acc[m][ni] = MFMA(aF[m], bF[ni], acc[m][ni]);                          \
    __builtin_amdgcn_s_setprio(0);                                             \
    /* next tile's stages landed (issued a full tile ago); rendezvous */       \
    asm volatile("s_waitcnt vmcnt(0)" ::: "memory");                           \
    __builtin_amdgcn_s_barrier();                                              \
  }

  // prologue: stage tile 0 (parity 0); wait; barrier
  stage(0);
  asm volatile("s_waitcnt vmcnt(0)" ::: "memory");
  __builtin_amdgcn_s_barrier();

  for (int kt2 = 0; kt2 < NT; kt2 += 2) {
    K_TILE(kt2, 0);
    K_TILE(kt2 + 1, 1);
  }
#undef K_TILE

  // epilogue: y = alpha*acc + bias.  C/D: col=l&15, row=4*(l>>4)+j (m89-verified)
  const float alpha = alpha_f[0];
#pragma unroll
  for (int ni = 0; ni < 8; ++ni) {
    const int col = tn * 256 + wc * 128 + ni * 16 + lr;
    const float bs = bias[col];
#pragma unroll
    for (int mi = 0; mi < 8; ++mi) {
      const int row = tm * 512 + wr * 128 + mi * 16 + lk * 4;
      float* Cp = C + (size_t)row * N_DIM + col;
#pragma unroll
      for (int j = 0; j < 4; ++j)
        Cp[(size_t)j * N_DIM] = alpha * acc[mi][ni][j] + bs;
    }
  }
}

extern "C" void kernel_launch(void* const* d_in, const int* in_sizes, int n_in,
                              void* d_out, int out_size, void* d_ws, size_t ws_size,
                              hipStream_t stream) {
  const float* x = (const float*)d_in[0];
  const float* w = (const float*)d_in[1];
  const float* bias = (const float*)d_in[2];
  float* out = (float*)d_out;

  char* ws = (char*)d_ws;
  double* alpha_d = (double*)ws;
  float* alpha_f = (float*)(ws + 8);
  double* partials = (double*)(ws + 16);
  u16* xb = (u16*)(ws + 65536);                 // 64 MiB (M*K bf16)
  u16* qb = (u16*)(ws + 65536 + 67108864ULL);   // 128 MiB (N*K bf16)

  reduce_abs1<<<4096, 256, 0, stream>>>(w, partials);
  reduce_abs2<<<1, 256, 0, stream>>>(partials, alpha_d, alpha_f);
  quant_w<<<32768, 256, 0, stream>>>(w, alpha_d, qb);
  conv_x<<<16384, 256, 0, stream>>>(x, xb);
  gemm256<<<1024, 512, 0, stream>>>(xb, qb, bias, alpha_f, out);
}

// Round 8
// 1155.839 us; speedup vs baseline: 5.6355x; 5.6355x over previous
//
#include <hip/hip_runtime.h>

// y = alpha*(x @ Q^T) + bias; alpha = mean|W|; Q = clip(round(W/alpha),-1,1)
// x:(2,4096,4096) f32, W:(16384,4096) f32, bias:(16384) f32, out f32.
#define M_DIM 8192
#define N_DIM 16384
#define K_DIM 4096
#define NT 64  // K_DIM / 64

typedef unsigned short u16;
typedef unsigned int u32;
typedef __attribute__((ext_vector_type(8))) short bf16x8;
typedef __attribute__((ext_vector_type(8))) unsigned short u16x8;
typedef __attribute__((ext_vector_type(4))) float f32x4;

#define MFMA(a, b, c) __builtin_amdgcn_mfma_f32_16x16x32_bf16(a, b, c, 0, 0, 0)
#define SGB(mask, n) __builtin_amdgcn_sched_group_barrier((mask), (n), 0)

__device__ __forceinline__ void gload16(const u16* g, u16* l) {
  __builtin_amdgcn_global_load_lds((const __attribute__((address_space(1))) void*)g,
                                   (__attribute__((address_space(3))) void*)l, 16, 0, 0);
}

// ---------------- alpha = mean(|W|), f64 two-pass reduction ----------------
__global__ void reduce_abs1(const float* __restrict__ w, double* __restrict__ partials) {
  const float4* w4 = (const float4*)w;
  size_t base = (size_t)blockIdx.x * 4096 + threadIdx.x;
  double s = 0.0;
#pragma unroll
  for (int i = 0; i < 16; ++i) {
    float4 v = w4[base + (size_t)i * 256];
    s += (double)fabsf(v.x); s += (double)fabsf(v.y);
    s += (double)fabsf(v.z); s += (double)fabsf(v.w);
  }
#pragma unroll
  for (int off = 32; off > 0; off >>= 1) s += __shfl_down(s, off, 64);
  __shared__ double red[4];
  int wv = threadIdx.x >> 6, lane = threadIdx.x & 63;
  if (lane == 0) red[wv] = s;
  __syncthreads();
  if (threadIdx.x == 0) partials[blockIdx.x] = (red[0] + red[1]) + (red[2] + red[3]);
}

__global__ void reduce_abs2(const double* __restrict__ partials,
                            double* __restrict__ alpha_d, float* __restrict__ alpha_f) {
  double s = 0.0;
  for (int i = threadIdx.x; i < 4096; i += 256) s += partials[i];
#pragma unroll
  for (int off = 32; off > 0; off >>= 1) s += __shfl_down(s, off, 64);
  __shared__ double red[4];
  int wv = threadIdx.x >> 6, lane = threadIdx.x & 63;
  if (lane == 0) red[wv] = s;
  __syncthreads();
  if (threadIdx.x == 0) {
    double total = (red[0] + red[1]) + (red[2] + red[3]);
    double a = total / (double)((long long)N_DIM * (long long)K_DIM);
    alpha_d[0] = a;
    alpha_f[0] = (float)a;
  }
}

// ---------------- W -> ternary Q stored as bf16 (+1/0/-1 exact) ----------------
__global__ void quant_w(const float* __restrict__ w, const double* __restrict__ alpha_d,
                        u16* __restrict__ q) {
  double inv = 1.0 / alpha_d[0];
  size_t i8 = (size_t)blockIdx.x * 256 + threadIdx.x;
  const float4* w4 = (const float4*)w;
  float4 v0 = w4[i8 * 2], v1 = w4[i8 * 2 + 1];
  float vv[8] = {v0.x, v0.y, v0.z, v0.w, v1.x, v1.y, v1.z, v1.w};
  u16x8 o;
#pragma unroll
  for (int j = 0; j < 8; ++j) {
    double r = rint((double)vv[j] * inv);
    u16 enc = 0;
    if (r >= 1.0) enc = 0x3F80u;
    else if (r <= -1.0) enc = 0xBF80u;
    o[j] = enc;
  }
  *((u16x8*)q + i8) = o;
}

// ---------------- x fp32 -> bf16 (RNE) ----------------
__global__ void conv_x(const float* __restrict__ x, u16* __restrict__ xb) {
  size_t i8 = (size_t)blockIdx.x * 256 + threadIdx.x;
  const float4* x4 = (const float4*)x;
  float4 v0 = x4[i8 * 2], v1 = x4[i8 * 2 + 1];
  float vv[8] = {v0.x, v0.y, v0.z, v0.w, v1.x, v1.y, v1.z, v1.w};
  u16x8 o;
#pragma unroll
  for (int j = 0; j < 8; ++j) {
    u32 u = __float_as_uint(vv[j]);
    u += 0x7FFFu + ((u >> 16) & 1u);
    o[j] = (u16)(u >> 16);
  }
  *((u16x8*)xb + i8) = o;
}

// ------- 256x256-tile bf16 GEMM, SGB fine-interleaved batch pipeline -------
// 512 threads = 8 waves (2M x 4N); per-wave 128x64 output = acc[8][4] f32x4
// (128 AGPR; wave budget 256 at 2 waves/SIMD -> VGPR must stay <= 128).
// LDS: 2 tile-buffers x {A 256x64, B 256x64} bf16 = 128 KiB.
// Diagnosis R3-R6: clustered read bursts + round-robin LDS arbitration lock
// all 8 waves in-phase -> LDS pipe (~2300cy) and matrix pipe (~2480cy)
// alternate instead of overlapping. Fix: 8 batches/K-tile of
// {<=4 ds_reads for batch j+1 | 8 MFMAs of batch j}, interleave PINNED with
// sched_group_barrier -> per round: LDS ~290cy vs matrix ~310cy, both busy.
// Frag sets: A0=A[m0-3]ks0, A1=A[m0-3]ks1, A2=A[m4-7]ks0, A3=A[m4-7]ks1;
// Ba0=B[n0-1]ks0, Bb0=B[n2-3]ks0, Ba1=B[n0-1]ks1, Bb1=B[n2-3]ks1.
// Reads/batch: pre6; {4,4,4,2,2,2,0,0} (1-batch lookahead). Stages (8 gloads,
// tile kt+1, OPPOSITE parity: never alias current reads) issue in b0/b1 ->
// ~2200cy before the tile-end vmcnt(0)+barrier (only barrier; R6-proven).
__global__ __launch_bounds__(512, 2) void gemm256(
    const u16* __restrict__ A, const u16* __restrict__ Bq,
    const float* __restrict__ bias, const float* __restrict__ alpha_f,
    float* __restrict__ C) {
  __shared__ __align__(16) u16 Alds[2][2][128 * 64];  // [parity][half][r*64+k]
  __shared__ __align__(16) u16 Blds[2][2][128 * 64];

  const int t = threadIdx.x;
  const int wv = t >> 6, l = t & 63;
  const int wr = wv >> 2, wc = wv & 3;  // 2M x 4N wave grid
  const int lr = l & 15, lk = l >> 4;

  // XCD-bijective swizzle (2048 % 8 == 0) + 8(tm) x 64(tn) supertiles
  const int bid = blockIdx.x;
  const int wg = (bid & 7) * 256 + (bid >> 3);
  const int grp = wg >> 9, rem = wg & 511;
  const int tm = grp * 8 + (rem & 7);  // 0..31
  const int tn = rem >> 3;             // 0..63

  const u16* Ag = A + (size_t)tm * 256 * K_DIM;
  const u16* Bg = Bq + (size_t)tn * 256 * K_DIM;

  // staging source offsets (pre-swizzled global source, linear LDS dest)
  const int q0 = t, q1 = 512 + t;
  const int r0 = q0 >> 3, c0 = (q0 & 7) ^ (r0 & 7);
  const int r1 = q1 >> 3, c1 = (q1 & 7) ^ (r1 & 7);
  const size_t so0 = (size_t)r0 * K_DIM + c0 * 8;
  const size_t so1 = (size_t)r1 * K_DIM + c1 * 8;
  const int do0 = (wv * 64) * 8;          // u16 units (wave-uniform dest base)
  const int do1 = (512 + wv * 64) * 8;

  // Swizzled frag read bases (u16 units). For frag row r = sub*16 + lr:
  // r&7 == lr&7, so offset = sub*1024 + fb[ks];  sub*1024 folds to imm offset.
  const int fb0 = lr * 64 + ((lk ^ (lr & 7)) * 8);
  const int fb1 = lr * 64 + (((4 + lk) ^ (lr & 7)) * 8);
#define LDF(ptr, sub, ks) (*(const bf16x8*)((ptr) + (sub) * 1024 + ((ks) ? fb1 : fb0)))

  f32x4 acc[8][4];
#pragma unroll
  for (int mi = 0; mi < 8; ++mi)
#pragma unroll
    for (int ni = 0; ni < 4; ++ni)
      acc[mi][ni] = (f32x4){0.f, 0.f, 0.f, 0.f};

  // stage one half-tile H (2 x global_load_lds per wave); no-op past last tile
  auto stage = [&](int H) {
    int g = H >> 2;
    if (g < NT) {
      int sub = H & 3;  // 0:B0 1:B1 2:A0 3:A1
      const u16* src;
      u16* dst;
      if (sub < 2) { src = Bg + (size_t)sub * (128 * K_DIM); dst = &Blds[g & 1][sub][0]; }
      else         { src = Ag + (size_t)(sub - 2) * (128 * K_DIM); dst = &Alds[g & 1][sub - 2][0]; }
      src += g * 64;
      gload16(src + so0, dst + do0);
      gload16(src + so1, dst + do1);
    }
  };

#define MFMA8(accrow, aset, bset, nbase)                                       \
  _Pragma("unroll") for (int m = 0; m < 4; ++m)                                \
    _Pragma("unroll") for (int n = 0; n < 2; ++n)                              \
      acc[(accrow) + m][(nbase) + n] = MFMA(aset[m], bset[n], acc[(accrow) + m][(nbase) + n])

  // one K-tile = pre-reads + 8 SGB-pinned {reads(j+1) | 8 MFMA(j)} batches
#define K_TILE(kt, par)                                                        \
  {                                                                            \
    const u16* Ar = &Alds[par][wr][0];                                         \
    const u16* Br = &Blds[par][wc >> 1][0] + (wc & 1) * 4096;                  \
    bf16x8 A0[4], A1[4], A2[4], A3[4], Ba0[2], Bb0[2], Ba1[2], Bb1[2];         \
    /* pre: A0(4) + Ba0(2) */                                                  \
    _Pragma("unroll") for (int m = 0; m < 4; ++m) A0[m] = LDF(Ar, m, 0);       \
    Ba0[0] = LDF(Br, 0, 0); Ba0[1] = LDF(Br, 1, 0);                            \
    SGB(0x100, 6);                                                             \
    /* b0: R{Bb0, A1[0-1]}; stage h0,h1(kt+1); M: acc[0-3][0-1]+=A0*Ba0 */     \
    Bb0[0] = LDF(Br, 2, 0); Bb0[1] = LDF(Br, 3, 0);                            \
    A1[0] = LDF(Ar, 0, 1); A1[1] = LDF(Ar, 1, 1);                              \
    stage(4 * (kt) + 4); stage(4 * (kt) + 5);                                  \
    MFMA8(0, A0, Ba0, 0);                                                      \
    SGB(0x100, 4); SGB(0x20, 4); SGB(0x8, 8);                                  \
    /* b1: R{A1[2-3], Ba1}; stage h2,h3(kt+1); M: acc[0-3][2-3]+=A0*Bb0 */     \
    A1[2] = LDF(Ar, 2, 1); A1[3] = LDF(Ar, 3, 1);                              \
    Ba1[0] = LDF(Br, 0, 1); Ba1[1] = LDF(Br, 1, 1);                            \
    stage(4 * (kt) + 6); stage(4 * (kt) + 7);                                  \
    MFMA8(0, A0, Bb0, 2);                                                      \
    SGB(0x100, 4); SGB(0x20, 4); SGB(0x8, 8);                                  \
    /* b2: R{Bb1, A2[0-1]}; M: acc[0-3][0-1]+=A1*Ba1 */                        \
    Bb1[0] = LDF(Br, 2, 1); Bb1[1] = LDF(Br, 3, 1);                            \
    A2[0] = LDF(Ar, 4, 0); A2[1] = LDF(Ar, 5, 0);                              \
    MFMA8(0, A1, Ba1, 0);                                                      \
    SGB(0x100, 4); SGB(0x8, 8);                                                \
    /* b3: R{A2[2-3]}; M: acc[0-3][2-3]+=A1*Bb1 */                             \
    A2[2] = LDF(Ar, 6, 0); A2[3] = LDF(Ar, 7, 0);                              \
    MFMA8(0, A1, Bb1, 2);                                                      \
    SGB(0x100, 2); SGB(0x8, 8);                                                \
    /* b4: R{A3[0-1]}; M: acc[4-7][0-1]+=A2*Ba0 */                             \
    A3[0] = LDF(Ar, 4, 1); A3[1] = LDF(Ar, 5, 1);                              \
    MFMA8(4, A2, Ba0, 0);                                                      \
    SGB(0x100, 2); SGB(0x8, 8);                                                \
    /* b5: R{A3[2-3]}; M: acc[4-7][2-3]+=A2*Bb0 */                             \
    A3[2] = LDF(Ar, 6, 1); A3[3] = LDF(Ar, 7, 1);                              \
    MFMA8(4, A2, Bb0, 2);                                                      \
    SGB(0x100, 2); SGB(0x8, 8);                                                \
    /* b6: M: acc[4-7][0-1]+=A3*Ba1 */                                         \
    MFMA8(4, A3, Ba1, 0);                                                      \
    SGB(0x8, 8);                                                               \
    /* b7: M: acc[4-7][2-3]+=A3*Bb1 */                                         \
    MFMA8(4, A3, Bb1, 2);                                                      \
    SGB(0x8, 8);                                                               \
    /* tile end: kt+1 stages (issued b0/b1) landed; rendezvous */              \
    asm volatile("s_waitcnt vmcnt(0)" ::: "memory");                           \
    __builtin_amdgcn_s_barrier();                                              \
  }

  // prologue: stage tile 0 (parity 0); wait; barrier
#pragma unroll
  for (int H = 0; H < 4; ++H) stage(H);
  asm volatile("s_waitcnt vmcnt(0)" ::: "memory");
  __builtin_amdgcn_s_barrier();

  for (int kt2 = 0; kt2 < NT; kt2 += 2) {
    K_TILE(kt2, 0);
    K_TILE(kt2 + 1, 1);
  }
#undef K_TILE
#undef MFMA8
#undef LDF

  // epilogue: y = alpha*acc + bias.  C/D: col=l&15, row=4*(l>>4)+j (m89-verified)
  const float alpha = alpha_f[0];
#pragma unroll
  for (int ni = 0; ni < 4; ++ni) {
    const int col = tn * 256 + wc * 64 + ni * 16 + lr;
    const float bs = bias[col];
#pragma unroll
    for (int mi = 0; mi < 8; ++mi) {
      const int row = tm * 256 + wr * 128 + mi * 16 + lk * 4;
      float* Cp = C + (size_t)row * N_DIM + col;
#pragma unroll
      for (int j = 0; j < 4; ++j)
        Cp[(size_t)j * N_DIM] = alpha * acc[mi][ni][j] + bs;
    }
  }
}

extern "C" void kernel_launch(void* const* d_in, const int* in_sizes, int n_in,
                              void* d_out, int out_size, void* d_ws, size_t ws_size,
                              hipStream_t stream) {
  const float* x = (const float*)d_in[0];
  const float* w = (const float*)d_in[1];
  const float* bias = (const float*)d_in[2];
  float* out = (float*)d_out;

  char* ws = (char*)d_ws;
  double* alpha_d = (double*)ws;
  float* alpha_f = (float*)(ws + 8);
  double* partials = (double*)(ws + 16);
  u16* xb = (u16*)(ws + 65536);                 // 64 MiB (M*K bf16)
  u16* qb = (u16*)(ws + 65536 + 67108864ULL);   // 128 MiB (N*K bf16)

  reduce_abs1<<<4096, 256, 0, stream>>>(w, partials);
  reduce_abs2<<<1, 256, 0, stream>>>(partials, alpha_d, alpha_f);
  quant_w<<<32768, 256, 0, stream>>>(w, alpha_d, qb);
  conv_x<<<16384, 256, 0, stream>>>(x, xb);
  gemm256<<<2048, 512, 0, stream>>>(xb, qb, bias, alpha_f, out);
}